// Round 1
// baseline (310.323 us; speedup 1.0000x reference)
//
#include <hip/hip_runtime.h>

typedef __bf16 bf16x8 __attribute__((ext_vector_type(8)));
typedef float  f32x4  __attribute__((ext_vector_type(4)));

#define TSEQ 2048
#define CDIM 1024
#define NHEAD 16
#define DH 64

// ---------------- fp32 -> bf16 conversion (vectorized) ----------------
__global__ __launch_bounds__(256) void cvt_bf16(const float* __restrict__ in,
                                                __bf16* __restrict__ out, int n8) {
  int i = blockIdx.x * 256 + threadIdx.x;
  if (i >= n8) return;
  const float4* p = (const float4*)(in + (size_t)i * 8);
  float4 a = p[0], b = p[1];
  bf16x8 r;
  r[0] = (__bf16)a.x; r[1] = (__bf16)a.y; r[2] = (__bf16)a.z; r[3] = (__bf16)a.w;
  r[4] = (__bf16)b.x; r[5] = (__bf16)b.y; r[6] = (__bf16)b.z; r[7] = (__bf16)b.w;
  *(bf16x8*)(out + (size_t)i * 8) = r;
}

// ---------------- bf16 GEMM: out[M,N] = A[M,K] * Bw[N,K]^T + bias ----------------
// EPI=0: write fp32 to outf.  EPI=1: scatter qkv -> q/k/vT bf16 buffers.
template <int EPI>
__global__ __launch_bounds__(256) void gemm_bt(
    const __bf16* __restrict__ A, const __bf16* __restrict__ Bw,
    const float* __restrict__ bias, float* __restrict__ outf,
    __bf16* __restrict__ q_buf, __bf16* __restrict__ k_buf,
    __bf16* __restrict__ vT_buf, int M, int N, int K) {
  __shared__ alignas(16) __bf16 lda[128][72];
  __shared__ alignas(16) __bf16 ldb[128][72];
  const int tid = threadIdx.x;
  const int lane = tid & 63, wid = tid >> 6;
  const int wm = wid >> 1, wn = wid & 1;  // 2x2 waves of 64x64
  const int row0 = blockIdx.y * 128, col0 = blockIdx.x * 128;
  f32x4 acc[4][4] = {};

  for (int k0 = 0; k0 < K; k0 += 64) {
    if (k0) __syncthreads();
#pragma unroll
    for (int i2 = 0; i2 < 4; ++i2) {
      int c = tid + i2 * 256;
      int r = c >> 3, off = (c & 7) * 8;
      *(bf16x8*)&lda[r][off] = *(const bf16x8*)&A[(size_t)(row0 + r) * K + k0 + off];
      *(bf16x8*)&ldb[r][off] = *(const bf16x8*)&Bw[(size_t)(col0 + r) * K + k0 + off];
    }
    __syncthreads();
#pragma unroll
    for (int kk = 0; kk < 2; ++kk) {
      bf16x8 af[4], bfr[4];
#pragma unroll
      for (int m = 0; m < 4; ++m)
        af[m] = *(const bf16x8*)&lda[wm * 64 + m * 16 + (lane & 15)][kk * 32 + (lane >> 4) * 8];
#pragma unroll
      for (int n = 0; n < 4; ++n)
        bfr[n] = *(const bf16x8*)&ldb[wn * 64 + n * 16 + (lane & 15)][kk * 32 + (lane >> 4) * 8];
#pragma unroll
      for (int m = 0; m < 4; ++m)
#pragma unroll
        for (int n = 0; n < 4; ++n)
          acc[m][n] = __builtin_amdgcn_mfma_f32_16x16x32_bf16(af[m], bfr[n], acc[m][n], 0, 0, 0);
    }
  }
  // epilogue: D layout col=lane&15, row=(lane>>4)*4+i
#pragma unroll
  for (int m = 0; m < 4; ++m) {
#pragma unroll
    for (int n = 0; n < 4; ++n) {
#pragma unroll
      for (int i = 0; i < 4; ++i) {
        int r = row0 + wm * 64 + m * 16 + (lane >> 4) * 4 + i;
        int c = col0 + wn * 64 + n * 16 + (lane & 15);
        float v = acc[m][n][i] + bias[c];
        if (EPI == 0) {
          outf[(size_t)r * N + c] = v;
        } else {
          int bb = r >> 11, t = r & 2047;       // r = b*T + t
          int sec = c >> 10, cc = c & 1023;     // 0:q 1:k 2:v
          int hh = cc >> 6, d = cc & 63;
          size_t bh = (size_t)bb * NHEAD + hh;
          __bf16 bv = (__bf16)v;
          if (sec == 0)      q_buf[(bh * TSEQ + (size_t)t) * DH + d] = bv;
          else if (sec == 1) k_buf[(bh * TSEQ + (size_t)t) * DH + d] = bv;
          else               vT_buf[(bh * DH + (size_t)d) * TSEQ + t] = bv;  // transposed
        }
      }
    }
  }
}

// ---------------- flash attention with ALiBi + causal ----------------
// grid: (T/64, B*H). 4 waves/block; wave w owns q-rows [qb+16w, qb+16w+16).
__global__ __launch_bounds__(256) void attn_fwd(
    const __bf16* __restrict__ q_buf, const __bf16* __restrict__ k_buf,
    const __bf16* __restrict__ vT_buf, __bf16* __restrict__ y_buf) {
  const int T = TSEQ;
  const int tid = threadIdx.x, lane = tid & 63, wid = tid >> 6;
  const int qt = blockIdx.x, bh = blockIdx.y;
  const int b = bh >> 4, h = bh & 15;
  const int qb = qt * 64;
  const float scale = 0.125f;  // 1/sqrt(64)
  const float slope = exp2f(-0.5f * (float)(h + 1));
  const __bf16* qp = q_buf + (size_t)bh * T * DH;
  const __bf16* kp = k_buf + (size_t)bh * T * DH;
  const __bf16* vp = vT_buf + (size_t)bh * DH * T;

  __shared__ alignas(16) __bf16 p_lds[4][16][72];

  // Q fragments (stay in registers for the whole kernel)
  bf16x8 qf[2];
  {
    int r = qb + wid * 16 + (lane & 15);
#pragma unroll
    for (int kk = 0; kk < 2; ++kk)
      qf[kk] = *(const bf16x8*)&qp[(size_t)r * DH + kk * 32 + (lane >> 4) * 8];
  }
  f32x4 o[4] = {};
  float mrow[4], lrow[4];
#pragma unroll
  for (int i = 0; i < 4; ++i) { mrow[i] = -__builtin_inff(); lrow[i] = 0.f; }
  const int qr0 = qb + wid * 16 + (lane >> 4) * 4;

  for (int kt = 0; kt <= qb; kt += 64) {
    // S = Q K^T  (16q x 64k per wave)
    f32x4 s[4];
#pragma unroll
    for (int n = 0; n < 4; ++n) {
      const __bf16* kr = &kp[(size_t)(kt + n * 16 + (lane & 15)) * DH + (lane >> 4) * 8];
      bf16x8 kf0 = *(const bf16x8*)kr;
      bf16x8 kf1 = *(const bf16x8*)(kr + 32);
      f32x4 z = {};
      z = __builtin_amdgcn_mfma_f32_16x16x32_bf16(qf[0], kf0, z, 0, 0, 0);
      s[n] = __builtin_amdgcn_mfma_f32_16x16x32_bf16(qf[1], kf1, z, 0, 0, 0);
    }
    // scale + ALiBi + causal mask; tile row-max
    float sv[4][4];
    float tmax[4] = {-__builtin_inff(), -__builtin_inff(), -__builtin_inff(), -__builtin_inff()};
#pragma unroll
    for (int n = 0; n < 4; ++n) {
      int kc = kt + n * 16 + (lane & 15);
#pragma unroll
      for (int i = 0; i < 4; ++i) {
        int r = qr0 + i;
        float x = (kc <= r) ? (s[n][i] * scale + slope * (float)(kc - r)) : -__builtin_inff();
        sv[n][i] = x;
        tmax[i] = fmaxf(tmax[i], x);
      }
    }
    // online softmax (per q-row; row spread over 16 lanes with same lane>>4)
    float pf[4][4];
#pragma unroll
    for (int i = 0; i < 4; ++i) {
      float t = tmax[i];
      t = fmaxf(t, __shfl_xor(t, 1));
      t = fmaxf(t, __shfl_xor(t, 2));
      t = fmaxf(t, __shfl_xor(t, 4));
      t = fmaxf(t, __shfl_xor(t, 8));
      float mnew = fmaxf(mrow[i], t);
      float corr = __expf(mrow[i] - mnew);  // exp(-inf - finite) = 0 on first tile
      mrow[i] = mnew;
      float rs = 0.f;
#pragma unroll
      for (int n = 0; n < 4; ++n) {
        float p = __expf(sv[n][i] - mnew);  // -inf -> 0 for masked
        pf[n][i] = p;
        rs += p;
      }
      rs += __shfl_xor(rs, 1); rs += __shfl_xor(rs, 2);
      rs += __shfl_xor(rs, 4); rs += __shfl_xor(rs, 8);
      lrow[i] = lrow[i] * corr + rs;
#pragma unroll
      for (int n2 = 0; n2 < 4; ++n2) o[n2][i] *= corr;
    }
    // P: D-layout -> A-layout via per-wave LDS region
#pragma unroll
    for (int n = 0; n < 4; ++n)
#pragma unroll
      for (int i = 0; i < 4; ++i)
        p_lds[wid][(lane >> 4) * 4 + i][n * 16 + (lane & 15)] = (__bf16)pf[n][i];
    __syncthreads();
    bf16x8 pa[2];
#pragma unroll
    for (int kk = 0; kk < 2; ++kk)
      pa[kk] = *(const bf16x8*)&p_lds[wid][lane & 15][kk * 32 + (lane >> 4) * 8];
    // O += P V  (B operand from vT rows, K-contiguous)
#pragma unroll
    for (int n2 = 0; n2 < 4; ++n2) {
      const __bf16* vr = &vp[(size_t)(n2 * 16 + (lane & 15)) * T + kt + (lane >> 4) * 8];
      bf16x8 vf0 = *(const bf16x8*)vr;
      bf16x8 vf1 = *(const bf16x8*)(vr + 32);
      o[n2] = __builtin_amdgcn_mfma_f32_16x16x32_bf16(pa[0], vf0, o[n2], 0, 0, 0);
      o[n2] = __builtin_amdgcn_mfma_f32_16x16x32_bf16(pa[1], vf1, o[n2], 0, 0, 0);
    }
    __syncthreads();
  }
  // normalize + write y in [B][T][H*64] layout (feeds proj GEMM)
#pragma unroll
  for (int i = 0; i < 4; ++i) {
    float inv = 1.0f / lrow[i];
    int t = qr0 + i;
#pragma unroll
    for (int n2 = 0; n2 < 4; ++n2) {
      int d = n2 * 16 + (lane & 15);
      y_buf[((size_t)b * T + t) * CDIM + h * DH + d] = (__bf16)(o[n2][i] * inv);
    }
  }
}

extern "C" void kernel_launch(void* const* d_in, const int* in_sizes, int n_in,
                              void* d_out, int out_size, void* d_ws, size_t ws_size,
                              hipStream_t stream) {
  const float* x      = (const float*)d_in[0];
  const float* W_attn = (const float*)d_in[1];
  const float* b_attn = (const float*)d_in[2];
  const float* W_proj = (const float*)d_in[3];
  const float* b_proj = (const float*)d_in[4];
  float* out = (float*)d_out;
  char* ws = (char*)d_ws;
  const size_t MB = (size_t)1 << 20;
  __bf16* xb  = (__bf16*)(ws + 0 * MB);   // 8 MB  x bf16 [4096][1024]
  __bf16* wab = (__bf16*)(ws + 8 * MB);   // 6 MB  W_attn bf16 [3072][1024]
  __bf16* wpb = (__bf16*)(ws + 14 * MB);  // 2 MB  W_proj bf16 [1024][1024]
  __bf16* qbf = (__bf16*)(ws + 16 * MB);  // 8 MB  q [BH][T][64]
  __bf16* kbf = (__bf16*)(ws + 24 * MB);  // 8 MB  k [BH][T][64]
  __bf16* vtb = (__bf16*)(ws + 32 * MB);  // 8 MB  v^T [BH][64][T]
  __bf16* yb  = (__bf16*)(ws + 40 * MB);  // 8 MB  y bf16 [4096][1024]

  cvt_bf16<<<2048, 256, 0, stream>>>(x, xb, 524288);
  cvt_bf16<<<1536, 256, 0, stream>>>(W_attn, wab, 393216);
  cvt_bf16<<<512, 256, 0, stream>>>(W_proj, wpb, 131072);

  // qkv = x @ W_attn^T + b_attn, scattered to q/k/vT
  gemm_bt<1><<<dim3(24, 32), 256, 0, stream>>>(xb, wab, b_attn, nullptr,
                                               qbf, kbf, vtb, 4096, 3072, 1024);
  // attention
  attn_fwd<<<dim3(32, 32), 256, 0, stream>>>(qbf, kbf, vtb, yb);
  // out = y @ W_proj^T + b_proj (fp32 out)
  gemm_bt<0><<<dim3(8, 32), 256, 0, stream>>>(yb, wpb, b_proj, out,
                                              nullptr, nullptr, nullptr, 4096, 1024, 1024);
}

// Round 2
// 280.341 us; speedup vs baseline: 1.1069x; 1.1069x over previous
//
#include <hip/hip_runtime.h>

typedef __bf16 bf16x8 __attribute__((ext_vector_type(8)));
typedef float  f32x4  __attribute__((ext_vector_type(4)));

#define TSEQ 2048
#define CDIM 1024
#define NHEAD 16
#define DH 64

__device__ __forceinline__ void gl_lds16(const void* g, void* l) {
  __builtin_amdgcn_global_load_lds(
      (const __attribute__((address_space(1))) unsigned int*)g,
      (__attribute__((address_space(3))) unsigned int*)l, 16, 0, 0);
}

// ---------------- fp32 -> bf16 conversion (vectorized) ----------------
__global__ __launch_bounds__(256) void cvt_bf16(const float* __restrict__ in,
                                                __bf16* __restrict__ out, int n8) {
  int i = blockIdx.x * 256 + threadIdx.x;
  if (i >= n8) return;
  const float4* p = (const float4*)(in + (size_t)i * 8);
  float4 a = p[0], b = p[1];
  bf16x8 r;
  r[0] = (__bf16)a.x; r[1] = (__bf16)a.y; r[2] = (__bf16)a.z; r[3] = (__bf16)a.w;
  r[4] = (__bf16)b.x; r[5] = (__bf16)b.y; r[6] = (__bf16)b.z; r[7] = (__bf16)b.w;
  *(bf16x8*)(out + (size_t)i * 8) = r;
}

// ---------------- bf16 GEMM (m97-style): out[M,N] = A[M,K]*Bw[N,K]^T + bias --------
// EPI=0: write fp32 to outf.  EPI=1: scatter qkv -> q/k/vT bf16 buffers.
template <int EPI>
__global__ __launch_bounds__(256) void gemm_bt(
    const __bf16* __restrict__ A, const __bf16* __restrict__ Bw,
    const float* __restrict__ bias, float* __restrict__ outf,
    __bf16* __restrict__ q_buf, __bf16* __restrict__ k_buf,
    __bf16* __restrict__ vT_buf, int M, int N, int K) {
  __shared__ alignas(16) __bf16 lda[128 * 64];  // 16KB, linear (global_load_lds dest)
  __shared__ alignas(16) __bf16 ldb[128 * 64];  // 16KB
  const int tid = threadIdx.x;
  const int lane = tid & 63, wid = tid >> 6;
  const int wm = wid >> 1, wn = wid & 1;  // 2x2 waves of 64x64
  const int row0 = blockIdx.y * 128, col0 = blockIdx.x * 128;
  f32x4 acc[4][4] = {};

  // staging geometry: wave wid, issue j covers LDS bytes [(j*4+wid)*1024, +1024)
  // lane l -> row (j*4+wid)*8 + l/8, byte-in-row (l&7)*16   (row = 128B)
  const int srow = lane >> 3;
  const int scb = (lane & 7) * 16;

  for (int k0 = 0; k0 < K; k0 += 64) {
#pragma unroll
    for (int j = 0; j < 4; ++j) {
      int blk = j * 4 + wid;
      int r = blk * 8 + srow;
      char* la = (char*)lda + blk * 1024;
      char* lb = (char*)ldb + blk * 1024;
      gl_lds16((const char*)(A + (size_t)(row0 + r) * K + k0) + scb, la);
      gl_lds16((const char*)(Bw + (size_t)(col0 + r) * K + k0) + scb, lb);
    }
    __syncthreads();  // compiler drains vmcnt(0) before barrier -> tiles ready
#pragma unroll
    for (int kk = 0; kk < 2; ++kk) {
      bf16x8 af[4], bfr[4];
#pragma unroll
      for (int m = 0; m < 4; ++m)
        af[m] = *(const bf16x8*)&lda[(wm * 64 + m * 16 + (lane & 15)) * 64 + kk * 32 + (lane >> 4) * 8];
#pragma unroll
      for (int n = 0; n < 4; ++n)
        bfr[n] = *(const bf16x8*)&ldb[(wn * 64 + n * 16 + (lane & 15)) * 64 + kk * 32 + (lane >> 4) * 8];
#pragma unroll
      for (int m = 0; m < 4; ++m)
#pragma unroll
        for (int n = 0; n < 4; ++n)
          acc[m][n] = __builtin_amdgcn_mfma_f32_16x16x32_bf16(af[m], bfr[n], acc[m][n], 0, 0, 0);
    }
    __syncthreads();  // all waves done reading before restage
  }
  // epilogue: D layout col=lane&15, row=(lane>>4)*4+i
#pragma unroll
  for (int m = 0; m < 4; ++m) {
#pragma unroll
    for (int n = 0; n < 4; ++n) {
#pragma unroll
      for (int i = 0; i < 4; ++i) {
        int r = row0 + wm * 64 + m * 16 + (lane >> 4) * 4 + i;
        int c = col0 + wn * 64 + n * 16 + (lane & 15);
        float v = acc[m][n][i] + bias[c];
        if (EPI == 0) {
          outf[(size_t)r * N + c] = v;
        } else {
          int bb = r >> 11, t = r & 2047;       // r = b*T + t
          int sec = c >> 10, cc = c & 1023;     // 0:q 1:k 2:v
          int hh = cc >> 6, d = cc & 63;
          size_t bh = (size_t)bb * NHEAD + hh;
          __bf16 bv = (__bf16)v;
          if (sec == 0)      q_buf[(bh * TSEQ + (size_t)t) * DH + d] = bv;
          else if (sec == 1) k_buf[(bh * TSEQ + (size_t)t) * DH + d] = bv;
          else               vT_buf[(bh * DH + (size_t)d) * TSEQ + t] = bv;  // transposed
        }
      }
    }
  }
}

// ---------------- flash attention with ALiBi + causal ----------------
// 1 wave per block; wave owns 32 q-rows. No barriers. K prefetch + early V issue.
// grid: (T/32, B*H), heavy-first on x.
__global__ __launch_bounds__(64) void attn_fwd(
    const __bf16* __restrict__ q_buf, const __bf16* __restrict__ k_buf,
    const __bf16* __restrict__ vT_buf, __bf16* __restrict__ y_buf) {
  const int T = TSEQ;
  const int lane = threadIdx.x;
  const int jq = (int)(gridDim.x - 1 - blockIdx.x);  // heavy blocks first
  const int bh = blockIdx.y;
  const int b = bh >> 4, h = bh & 15;
  const int qb = jq * 32;  // rows [qb, qb+32)
  const float scale = 0.125f;
  const float slope = exp2f(-0.5f * (float)(h + 1));
  const __bf16* qp = q_buf + (size_t)bh * T * DH;
  const __bf16* kp = k_buf + (size_t)bh * T * DH;
  const __bf16* vp = vT_buf + (size_t)bh * DH * T;

  __shared__ alignas(16) __bf16 p_lds[32][72];

  // Q fragments: rows qb + m*16 + (lane&15)
  bf16x8 qf[2][2];
#pragma unroll
  for (int m = 0; m < 2; ++m) {
    const __bf16* qr = &qp[(size_t)(qb + m * 16 + (lane & 15)) * DH + (lane >> 4) * 8];
#pragma unroll
    for (int kk = 0; kk < 2; ++kk) qf[m][kk] = *(const bf16x8*)(qr + kk * 32);
  }

  f32x4 o[2][4] = {};
  float mrow[2][4], lrow[2][4];
#pragma unroll
  for (int m = 0; m < 2; ++m)
#pragma unroll
    for (int i = 0; i < 4; ++i) { mrow[m][i] = -__builtin_inff(); lrow[m][i] = 0.f; }

  const int klo = (lane & 15) * DH + (lane >> 4) * 8;   // K per-lane offset
  const int vlo = (lane & 15) * T + (lane >> 4) * 8;    // V^T per-lane offset
  const int kt_end = qb + 31;

  // prefetch K tile 0
  bf16x8 kf[4][2];
#pragma unroll
  for (int n = 0; n < 4; ++n) {
    const __bf16* kr = kp + n * 16 * DH + klo;
    kf[n][0] = *(const bf16x8*)kr;
    kf[n][1] = *(const bf16x8*)(kr + 32);
  }

  for (int kt = 0; kt <= kt_end; kt += 64) {
    // issue V loads for current tile early (latency hides under QK+softmax)
    bf16x8 vf[4][2];
#pragma unroll
    for (int n2 = 0; n2 < 4; ++n2) {
      const __bf16* vr = vp + vlo + n2 * 16 * T + kt;
      vf[n2][0] = *(const bf16x8*)vr;
      vf[n2][1] = *(const bf16x8*)(vr + 32);
    }
    // prefetch next K tile
    bf16x8 kn[4][2];
    if (kt + 64 <= kt_end) {
#pragma unroll
      for (int n = 0; n < 4; ++n) {
        const __bf16* kr = kp + (size_t)(kt + 64 + n * 16) * DH + klo;
        kn[n][0] = *(const bf16x8*)kr;
        kn[n][1] = *(const bf16x8*)(kr + 32);
      }
    }
    // S = Q K^T, softmax, P->LDS (per m-group of 16 rows)
#pragma unroll
    for (int m = 0; m < 2; ++m) {
      f32x4 s[4];
#pragma unroll
      for (int n = 0; n < 4; ++n) {
        f32x4 z = {};
        z = __builtin_amdgcn_mfma_f32_16x16x32_bf16(qf[m][0], kf[n][0], z, 0, 0, 0);
        s[n] = __builtin_amdgcn_mfma_f32_16x16x32_bf16(qf[m][1], kf[n][1], z, 0, 0, 0);
      }
      const int qr0 = qb + m * 16 + (lane >> 4) * 4;
      float sv[4][4];
      float tmax[4] = {-__builtin_inff(), -__builtin_inff(), -__builtin_inff(), -__builtin_inff()};
#pragma unroll
      for (int n = 0; n < 4; ++n) {
        int kc = kt + n * 16 + (lane & 15);
#pragma unroll
        for (int i = 0; i < 4; ++i) {
          int r = qr0 + i;
          float x = (kc <= r) ? (s[n][i] * scale + slope * (float)(kc - r)) : -__builtin_inff();
          sv[n][i] = x;
          tmax[i] = fmaxf(tmax[i], x);
        }
      }
#pragma unroll
      for (int i = 0; i < 4; ++i) {
        float t = tmax[i];
        t = fmaxf(t, __shfl_xor(t, 1));
        t = fmaxf(t, __shfl_xor(t, 2));
        t = fmaxf(t, __shfl_xor(t, 4));
        t = fmaxf(t, __shfl_xor(t, 8));
        float mnew = fmaxf(mrow[m][i], t);
        float corr = __expf(mrow[m][i] - mnew);
        mrow[m][i] = mnew;
        float rs = 0.f;
        float pf[4];
#pragma unroll
        for (int n = 0; n < 4; ++n) {
          pf[n] = __expf(sv[n][i] - mnew);
          rs += pf[n];
        }
        rs += __shfl_xor(rs, 1); rs += __shfl_xor(rs, 2);
        rs += __shfl_xor(rs, 4); rs += __shfl_xor(rs, 8);
        lrow[m][i] = lrow[m][i] * corr + rs;
#pragma unroll
        for (int n2 = 0; n2 < 4; ++n2) o[m][n2][i] *= corr;
#pragma unroll
        for (int n = 0; n < 4; ++n)
          p_lds[m * 16 + (lane >> 4) * 4 + i][n * 16 + (lane & 15)] = (__bf16)pf[n];
      }
    }
    // P (A-frag) from per-wave LDS; PV
#pragma unroll
    for (int m = 0; m < 2; ++m) {
      bf16x8 pa[2];
#pragma unroll
      for (int kk = 0; kk < 2; ++kk)
        pa[kk] = *(const bf16x8*)&p_lds[m * 16 + (lane & 15)][kk * 32 + (lane >> 4) * 8];
#pragma unroll
      for (int n2 = 0; n2 < 4; ++n2) {
        o[m][n2] = __builtin_amdgcn_mfma_f32_16x16x32_bf16(pa[0], vf[n2][0], o[m][n2], 0, 0, 0);
        o[m][n2] = __builtin_amdgcn_mfma_f32_16x16x32_bf16(pa[1], vf[n2][1], o[m][n2], 0, 0, 0);
      }
    }
#pragma unroll
    for (int n = 0; n < 4; ++n) {
      kf[n][0] = kn[n][0];
      kf[n][1] = kn[n][1];
    }
  }
  // normalize + write y in [B][T][C] layout
#pragma unroll
  for (int m = 0; m < 2; ++m) {
#pragma unroll
    for (int i = 0; i < 4; ++i) {
      float inv = 1.0f / lrow[m][i];
      int t = qb + m * 16 + (lane >> 4) * 4 + i;
#pragma unroll
      for (int n2 = 0; n2 < 4; ++n2) {
        int d = n2 * 16 + (lane & 15);
        y_buf[((size_t)b * T + t) * CDIM + h * DH + d] = (__bf16)(o[m][n2][i] * inv);
      }
    }
  }
}

extern "C" void kernel_launch(void* const* d_in, const int* in_sizes, int n_in,
                              void* d_out, int out_size, void* d_ws, size_t ws_size,
                              hipStream_t stream) {
  const float* x      = (const float*)d_in[0];
  const float* W_attn = (const float*)d_in[1];
  const float* b_attn = (const float*)d_in[2];
  const float* W_proj = (const float*)d_in[3];
  const float* b_proj = (const float*)d_in[4];
  float* out = (float*)d_out;
  char* ws = (char*)d_ws;
  const size_t MB = (size_t)1 << 20;
  __bf16* xb  = (__bf16*)(ws + 0 * MB);
  __bf16* wab = (__bf16*)(ws + 8 * MB);
  __bf16* wpb = (__bf16*)(ws + 14 * MB);
  __bf16* qbf = (__bf16*)(ws + 16 * MB);
  __bf16* kbf = (__bf16*)(ws + 24 * MB);
  __bf16* vtb = (__bf16*)(ws + 32 * MB);
  __bf16* yb  = (__bf16*)(ws + 40 * MB);

  cvt_bf16<<<2048, 256, 0, stream>>>(x, xb, 524288);
  cvt_bf16<<<1536, 256, 0, stream>>>(W_attn, wab, 393216);
  cvt_bf16<<<512, 256, 0, stream>>>(W_proj, wpb, 131072);

  gemm_bt<1><<<dim3(24, 32), 256, 0, stream>>>(xb, wab, b_attn, nullptr,
                                               qbf, kbf, vtb, 4096, 3072, 1024);
  attn_fwd<<<dim3(64, 32), 64, 0, stream>>>(qbf, kbf, vtb, yb);
  gemm_bt<0><<<dim3(8, 32), 256, 0, stream>>>(yb, wpb, b_proj, out,
                                              nullptr, nullptr, nullptr, 4096, 1024, 1024);
}

// Round 4
// 200.504 us; speedup vs baseline: 1.5477x; 1.3982x over previous
//
#include <hip/hip_runtime.h>

typedef __bf16 bf16x8 __attribute__((ext_vector_type(8)));
typedef float  f32x4  __attribute__((ext_vector_type(4)));

#define TSEQ 2048
#define CDIM 1024
#define NHEAD 16
#define DH 64

__device__ __forceinline__ void gl_lds16(const void* g, void* l) {
  __builtin_amdgcn_global_load_lds(
      (const __attribute__((address_space(1))) unsigned int*)g,
      (__attribute__((address_space(3))) unsigned int*)l, 16, 0, 0);
}

template <int PAT>
__device__ __forceinline__ float swz(float x) {
  return __int_as_float(__builtin_amdgcn_ds_swizzle(__float_as_int(x), PAT));
}

// fast 2^x: v_exp_f32
__device__ __forceinline__ float fexp2(float x) { return __builtin_amdgcn_exp2f(x); }

// ---------------- fp32 -> bf16 conversion (vectorized) ----------------
__global__ __launch_bounds__(256) void cvt_bf16(const float* __restrict__ in,
                                                __bf16* __restrict__ out, int n8) {
  int i = blockIdx.x * 256 + threadIdx.x;
  if (i >= n8) return;
  const float4* p = (const float4*)(in + (size_t)i * 8);
  float4 a = p[0], b = p[1];
  bf16x8 r;
  r[0] = (__bf16)a.x; r[1] = (__bf16)a.y; r[2] = (__bf16)a.z; r[3] = (__bf16)a.w;
  r[4] = (__bf16)b.x; r[5] = (__bf16)b.y; r[6] = (__bf16)b.z; r[7] = (__bf16)b.w;
  *(bf16x8*)(out + (size_t)i * 8) = r;
}

// ---------------- bf16 GEMM (m97-style): out[M,N] = A[M,K]*Bw[N,K]^T + bias --------
template <int EPI>
__global__ __launch_bounds__(256) void gemm_bt(
    const __bf16* __restrict__ A, const __bf16* __restrict__ Bw,
    const float* __restrict__ bias, float* __restrict__ outf,
    __bf16* __restrict__ q_buf, __bf16* __restrict__ k_buf,
    __bf16* __restrict__ vT_buf, int M, int N, int K) {
  __shared__ alignas(16) __bf16 lda[128 * 64];
  __shared__ alignas(16) __bf16 ldb[128 * 64];
  const int tid = threadIdx.x;
  const int lane = tid & 63, wid = tid >> 6;
  const int wm = wid >> 1, wn = wid & 1;
  const int row0 = blockIdx.y * 128, col0 = blockIdx.x * 128;
  f32x4 acc[4][4] = {};

  const int srow = lane >> 3;
  const int scb = (lane & 7) * 16;

  for (int k0 = 0; k0 < K; k0 += 64) {
#pragma unroll
    for (int j = 0; j < 4; ++j) {
      int blk = j * 4 + wid;
      int r = blk * 8 + srow;
      char* la = (char*)lda + blk * 1024;
      char* lb = (char*)ldb + blk * 1024;
      gl_lds16((const char*)(A + (size_t)(row0 + r) * K + k0) + scb, la);
      gl_lds16((const char*)(Bw + (size_t)(col0 + r) * K + k0) + scb, lb);
    }
    __syncthreads();
#pragma unroll
    for (int kk = 0; kk < 2; ++kk) {
      bf16x8 af[4], bfr[4];
#pragma unroll
      for (int m = 0; m < 4; ++m)
        af[m] = *(const bf16x8*)&lda[(wm * 64 + m * 16 + (lane & 15)) * 64 + kk * 32 + (lane >> 4) * 8];
#pragma unroll
      for (int n = 0; n < 4; ++n)
        bfr[n] = *(const bf16x8*)&ldb[(wn * 64 + n * 16 + (lane & 15)) * 64 + kk * 32 + (lane >> 4) * 8];
#pragma unroll
      for (int m = 0; m < 4; ++m)
#pragma unroll
        for (int n = 0; n < 4; ++n)
          acc[m][n] = __builtin_amdgcn_mfma_f32_16x16x32_bf16(af[m], bfr[n], acc[m][n], 0, 0, 0);
    }
    __syncthreads();
  }
#pragma unroll
  for (int m = 0; m < 4; ++m) {
#pragma unroll
    for (int n = 0; n < 4; ++n) {
#pragma unroll
      for (int i = 0; i < 4; ++i) {
        int r = row0 + wm * 64 + m * 16 + (lane >> 4) * 4 + i;
        int c = col0 + wn * 64 + n * 16 + (lane & 15);
        float v = acc[m][n][i] + bias[c];
        if (EPI == 0) {
          outf[(size_t)r * N + c] = v;
        } else {
          int bb = r >> 11, t = r & 2047;
          int sec = c >> 10, cc = c & 1023;
          int hh = cc >> 6, d = cc & 63;
          size_t bh = (size_t)bb * NHEAD + hh;
          __bf16 bv = (__bf16)v;
          if (sec == 0)      q_buf[(bh * TSEQ + (size_t)t) * DH + d] = bv;
          else if (sec == 1) k_buf[(bh * TSEQ + (size_t)t) * DH + d] = bv;
          else               vT_buf[(bh * DH + (size_t)d) * TSEQ + t] = bv;
        }
      }
    }
  }
}

// ---------------- flash attention: heavy+light paired, base-2 softmax ----------------
// 1 wave/block. Wave wv owns 16-row groups {wv (light), 127-wv (heavy)} of one bh.
// grid (bh=32, wv=64): linear id % 8 == bh % 8 -> each XCD serves 4 heads (L2-fit).
__device__ __forceinline__ void qk_softmax_p(
    int kt, int qrow0, int lane, float scale2, float slope2,
    const bf16x8* qf, const bf16x8 (*kf)[2],
    f32x4* o, float* mrow, float* lrow, __bf16 (*p)[72]) {
  f32x4 s[4];
#pragma unroll
  for (int n = 0; n < 4; ++n) {
    f32x4 z = {};
    z = __builtin_amdgcn_mfma_f32_16x16x32_bf16(qf[0], kf[n][0], z, 0, 0, 0);
    s[n] = __builtin_amdgcn_mfma_f32_16x16x32_bf16(qf[1], kf[n][1], z, 0, 0, 0);
  }
  const int qr0 = qrow0 + (lane >> 4) * 4;
  float sv[4][4];
  float tmax[4] = {-__builtin_inff(), -__builtin_inff(), -__builtin_inff(), -__builtin_inff()};
#pragma unroll
  for (int n = 0; n < 4; ++n) {
    int kc = kt + n * 16 + (lane & 15);
#pragma unroll
    for (int i = 0; i < 4; ++i) {
      int r = qr0 + i;
      float x = (kc <= r) ? (s[n][i] * scale2 + slope2 * (float)(kc - r)) : -__builtin_inff();
      sv[n][i] = x;
      tmax[i] = fmaxf(tmax[i], x);
    }
  }
#pragma unroll
  for (int i = 0; i < 4; ++i) {
    float t = tmax[i];
    t = fmaxf(t, swz<0x041F>(t));
    t = fmaxf(t, swz<0x081F>(t));
    t = fmaxf(t, swz<0x101F>(t));
    t = fmaxf(t, swz<0x201F>(t));
    float mnew = fmaxf(mrow[i], t);
    float corr = fexp2(mrow[i] - mnew);
    mrow[i] = mnew;
    float rs = 0.f;
    float pf[4];
#pragma unroll
    for (int n = 0; n < 4; ++n) {
      pf[n] = fexp2(sv[n][i] - mnew);
      rs += pf[n];
    }
    rs += swz<0x041F>(rs);
    rs += swz<0x081F>(rs);
    rs += swz<0x101F>(rs);
    rs += swz<0x201F>(rs);
    lrow[i] = lrow[i] * corr + rs;
#pragma unroll
    for (int n2 = 0; n2 < 4; ++n2) o[n2][i] *= corr;
#pragma unroll
    for (int n = 0; n < 4; ++n)
      p[(lane >> 4) * 4 + i][n * 16 + (lane & 15)] = (__bf16)pf[n];
  }
}

__device__ __forceinline__ void pv_acc(
    int lane, const bf16x8 (*vf)[2], f32x4* o, const __bf16 (*p)[72]) {
  bf16x8 pa[2];
#pragma unroll
  for (int kk = 0; kk < 2; ++kk)
    pa[kk] = *(const bf16x8*)&p[lane & 15][kk * 32 + (lane >> 4) * 8];
#pragma unroll
  for (int n2 = 0; n2 < 4; ++n2) {
    o[n2] = __builtin_amdgcn_mfma_f32_16x16x32_bf16(pa[0], vf[n2][0], o[n2], 0, 0, 0);
    o[n2] = __builtin_amdgcn_mfma_f32_16x16x32_bf16(pa[1], vf[n2][1], o[n2], 0, 0, 0);
  }
}

__global__ __launch_bounds__(64) void attn_fwd(
    const __bf16* __restrict__ q_buf, const __bf16* __restrict__ k_buf,
    const __bf16* __restrict__ vT_buf, __bf16* __restrict__ y_buf) {
  const int T = TSEQ;
  const int lane = threadIdx.x;
  const int bh = blockIdx.x;
  const int wv = blockIdx.y;
  const int b = bh >> 4, h = bh & 15;
  const int row0[2] = {(127 - wv) * 16, wv * 16};  // 0=heavy, 1=light
  const float scale2 = 0.125f * 1.44269504f;
  const float slope2 = exp2f(-0.5f * (float)(h + 1)) * 1.44269504f;
  const __bf16* qp = q_buf + (size_t)bh * T * DH;
  const __bf16* kp = k_buf + (size_t)bh * T * DH;
  const __bf16* vp = vT_buf + (size_t)bh * DH * T;

  __shared__ alignas(16) __bf16 p_lds[2][16][72];

  bf16x8 qf[2][2];
#pragma unroll
  for (int g = 0; g < 2; ++g) {
    const __bf16* qr = &qp[(size_t)(row0[g] + (lane & 15)) * DH + (lane >> 4) * 8];
#pragma unroll
    for (int kk = 0; kk < 2; ++kk) qf[g][kk] = *(const bf16x8*)(qr + kk * 32);
  }

  f32x4 o[2][4] = {};
  float mrow[2][4], lrow[2][4];
#pragma unroll
  for (int g = 0; g < 2; ++g)
#pragma unroll
    for (int i = 0; i < 4; ++i) { mrow[g][i] = -__builtin_inff(); lrow[g][i] = 0.f; }

  const int klo = (lane & 15) * DH + (lane >> 4) * 8;
  const int vlo = (lane & 15) * T + (lane >> 4) * 8;
  const int hend = row0[0] + 15;  // heavy group governs loop & loads
  const int lend = row0[1] + 15;

  bf16x8 kf[4][2];
#pragma unroll
  for (int n = 0; n < 4; ++n) {
    const __bf16* kr = kp + n * 16 * DH + klo;
    kf[n][0] = *(const bf16x8*)kr;
    kf[n][1] = *(const bf16x8*)(kr + 32);
  }

  for (int kt = 0; kt <= hend; kt += 64) {
    bf16x8 vf[4][2];
#pragma unroll
    for (int n2 = 0; n2 < 4; ++n2) {
      const __bf16* vr = vp + vlo + n2 * 16 * T + kt;
      vf[n2][0] = *(const bf16x8*)vr;
      vf[n2][1] = *(const bf16x8*)(vr + 32);
    }
    bf16x8 kn[4][2];
    if (kt + 64 <= hend) {
#pragma unroll
      for (int n = 0; n < 4; ++n) {
        const __bf16* kr = kp + (size_t)(kt + 64 + n * 16) * DH + klo;
        kn[n][0] = *(const bf16x8*)kr;
        kn[n][1] = *(const bf16x8*)(kr + 32);
      }
    }
    const bool lact = (kt <= lend);
    qk_softmax_p(kt, row0[0], lane, scale2, slope2, qf[0], kf,
                 o[0], mrow[0], lrow[0], p_lds[0]);
    if (lact)
      qk_softmax_p(kt, row0[1], lane, scale2, slope2, qf[1], kf,
                   o[1], mrow[1], lrow[1], p_lds[1]);
    pv_acc(lane, vf, o[0], p_lds[0]);
    if (lact) pv_acc(lane, vf, o[1], p_lds[1]);
#pragma unroll
    for (int n = 0; n < 4; ++n) {
      kf[n][0] = kn[n][0];
      kf[n][1] = kn[n][1];
    }
  }
#pragma unroll
  for (int g = 0; g < 2; ++g) {
#pragma unroll
    for (int i = 0; i < 4; ++i) {
      float inv = 1.0f / lrow[g][i];
      int t = row0[g] + (lane >> 4) * 4 + i;
#pragma unroll
      for (int n2 = 0; n2 < 4; ++n2) {
        int d = n2 * 16 + (lane & 15);
        y_buf[((size_t)b * T + t) * CDIM + h * DH + d] = (__bf16)(o[g][n2][i] * inv);
      }
    }
  }
}

extern "C" void kernel_launch(void* const* d_in, const int* in_sizes, int n_in,
                              void* d_out, int out_size, void* d_ws, size_t ws_size,
                              hipStream_t stream) {
  const float* x      = (const float*)d_in[0];
  const float* W_attn = (const float*)d_in[1];
  const float* b_attn = (const float*)d_in[2];
  const float* W_proj = (const float*)d_in[3];
  const float* b_proj = (const float*)d_in[4];
  float* out = (float*)d_out;
  char* ws = (char*)d_ws;
  const size_t MB = (size_t)1 << 20;
  __bf16* xb  = (__bf16*)(ws + 0 * MB);
  __bf16* wab = (__bf16*)(ws + 8 * MB);
  __bf16* wpb = (__bf16*)(ws + 14 * MB);
  __bf16* qbf = (__bf16*)(ws + 16 * MB);
  __bf16* kbf = (__bf16*)(ws + 24 * MB);
  __bf16* vtb = (__bf16*)(ws + 32 * MB);
  __bf16* yb  = (__bf16*)(ws + 40 * MB);

  cvt_bf16<<<2048, 256, 0, stream>>>(x, xb, 524288);
  cvt_bf16<<<1536, 256, 0, stream>>>(W_attn, wab, 393216);
  cvt_bf16<<<512, 256, 0, stream>>>(W_proj, wpb, 131072);

  gemm_bt<1><<<dim3(24, 32), 256, 0, stream>>>(xb, wab, b_attn, nullptr,
                                               qbf, kbf, vtb, 4096, 3072, 1024);
  attn_fwd<<<dim3(32, 64), 64, 0, stream>>>(qbf, kbf, vtb, yb);
  gemm_bt<0><<<dim3(8, 32), 256, 0, stream>>>(yb, wpb, b_proj, out,
                                              nullptr, nullptr, nullptr, 4096, 1024, 1024);
}